// Round 7
// baseline (131.784 us; speedup 1.0000x reference)
//
#include <hip/hip_runtime.h>
#include <hip/hip_bf16.h>
#include <cstdint>

#define HW 128
#define MASK_ELEMS (HW * HW)
#define SBLK 1024      // sampler block size (16 waves)
#define NBLK 256       // sampler grid size (1 block/CU by LDS; work-stealing handles placement)

typedef unsigned short ushort_t;
typedef __attribute__((ext_vector_type(4))) unsigned short ushort4_t;
typedef __attribute__((ext_vector_type(8))) short short8;
typedef __attribute__((ext_vector_type(4))) float f32x4;

__device__ __forceinline__ float asf(unsigned int u) {
    union { unsigned int i; float f; } c;
    c.i = u;
    return c.f;
}
__device__ __forceinline__ ushort_t f2bf(float f) {
    union { float f; unsigned int i; } c;
    c.f = f;
    unsigned int r = c.i + 0x7FFFu + ((c.i >> 16) & 1u);  // RNE
    return (ushort_t)(r >> 16);
}

// ---------- kernel 1: per-point bilinear setup -> base idx + 4 packed bf16 weight products ----
// Base b clamped so bx<=126, by<=126: taps {b, b+1, b+128, b+129} all in [0,16384).
// Also zeroes the work-stealing counter for ksamp_all (must happen every launch/replay).
__global__ void kprep(const float* __restrict__ coords, int* __restrict__ idx,
                      uint2* __restrict__ wpk, int* __restrict__ ctr, int P) {
    if (blockIdx.x == 0 && threadIdx.x == 0) *ctr = 0;
    int i = blockIdx.x * 256 + threadIdx.x;
    if (i >= P) return;
    float cx = coords[2 * i], cy = coords[2 * i + 1];
    float x = cx * (float)HW - 0.5f;
    float y = cy * (float)HW - 0.5f;
    float x0f = floorf(x), y0f = floorf(y);
    float wx1 = x - x0f, wy1 = y - y0f;
    float wx0 = 1.f - wx1, wy0 = 1.f - wy1;
    int x0 = (int)x0f, y0 = (int)y0f;

    float wxA = (x0 >= 0) ? wx0 : wx1;
    float wxB = (x0 >= 0 && x0 < HW - 1) ? wx1 : 0.f;
    float wyA = (y0 >= 0) ? wy0 : wy1;
    float wyB = (y0 >= 0 && y0 < HW - 1) ? wy1 : 0.f;
    int bx = max(x0, 0), by = max(y0, 0);
    if (bx > HW - 2) { bx = HW - 2; wxB = wxA; wxA = 0.f; }
    if (by > HW - 2) { by = HW - 2; wyB = wyA; wyA = 0.f; }

    idx[i] = by * HW + bx;
    wpk[i] = make_uint2((unsigned)f2bf(wxA * wyA) | ((unsigned)f2bf(wxB * wyA) << 16),
                        (unsigned)f2bf(wxA * wyB) | ((unsigned)f2bf(wxB * wyB) << 16));
}

// ---------- kernel 2: persistent fused sampler (pred + tgt masks), work-stealing ----------
// 128KB LDS double-buffer; async global_load_lds stages the next stolen mask while sampling
// the current one. Point metadata lives in registers (mask-invariant) so the sample loop
// issues no vmem reads. Per-wave row-sum partials go straight to global (spart[16][NM]);
// their values depend only on (wave, mask) -> bit-deterministic under any work assignment.
__device__ __forceinline__ void stage_mask(const float* __restrict__ g, float* l, int tid) {
    #pragma unroll
    for (int j = 0; j < MASK_ELEMS / (SBLK * 4); ++j) {   // 4 x 16B per thread
        int o = j * SBLK * 4 + tid * 4;
        __builtin_amdgcn_global_load_lds(
            (const __attribute__((address_space(1))) unsigned int*)(const void*)(g + o),
            (__attribute__((address_space(3))) unsigned int*)(void*)(l + o), 16, 0, 0);
    }
}

__global__ __launch_bounds__(SBLK, 4) void ksamp_all(
        const float* __restrict__ pmask, const float* __restrict__ tmasks,
        const int* __restrict__ idx, const uint2* __restrict__ wpk,
        ushort_t* __restrict__ S, ushort_t* __restrict__ tsamp,
        float* __restrict__ spart, int* __restrict__ ctr,
        const int* __restrict__ lvl, int N, int T, int P) {
    if (*lvl >= 2) return;
    __shared__ float buf[2][MASK_ELEMS];     // 128 KB
    __shared__ int sh_mi[2];                 // parity-double-buffered next-mask slot
    int tid = threadIdx.x;
    int NM = N + T;
    int nq = P >> 2;                          // point-quads

    // ---- preload mask-invariant point metadata into registers ----
    int4 idr[4];
    uint4 war[4], wbr[4];
    #pragma unroll
    for (int it = 0; it < 4; ++it) {
        int q = it * SBLK + tid;
        if (q < nq) {
            idr[it] = ((const int4*)idx)[q];
            war[it] = ((const uint4*)wpk)[2 * q];
            wbr[it] = ((const uint4*)wpk)[2 * q + 1];
        } else {
            idr[it] = make_int4(0, 0, 0, 0);
            war[it] = make_uint4(0, 0, 0, 0);
            wbr[it] = make_uint4(0, 0, 0, 0);
        }
    }

    if (tid == 0) sh_mi[0] = atomicAdd(ctr, 1);
    __syncthreads();
    int mi = sh_mi[0];
    if (mi < NM) {
        const float* m0 = (mi < N) ? pmask + (size_t)mi * MASK_ELEMS
                                   : tmasks + (size_t)(mi - N) * MASK_ELEMS;
        stage_mask(m0, buf[0], tid);
    }
    if (tid == 0) sh_mi[1] = (mi < NM) ? atomicAdd(ctr, 1) : NM;

    int cur = 0, p = 1;
    while (mi < NM) {
        asm volatile("s_waitcnt vmcnt(0)" ::: "memory");   // buf[cur]'s stage landed
        __syncthreads();                                    // + publishes sh_mi[p]
        int nmi = sh_mi[p];
        if (nmi < NM) {                       // issue next mask's stage (overlaps sampling)
            const float* mn = (nmi < N) ? pmask + (size_t)nmi * MASK_ELEMS
                                        : tmasks + (size_t)(nmi - N) * MASK_ELEMS;
            stage_mask(mn, buf[cur ^ 1], tid);
        }
        if (tid == 0) sh_mi[p ^ 1] = (nmi < NM) ? atomicAdd(ctr, 1) : NM;

        const float* lm = buf[cur];
        bool sig = (mi < N);
        ushort4_t* o4 = sig ? (ushort4_t*)(S + (size_t)mi * P)
                            : (ushort4_t*)(tsamp + (size_t)(mi - N) * P);
        float sum = 0.f;
        #pragma unroll
        for (int it = 0; it < 4; ++it) {
            int q = it * SBLK + tid;
            if (q < nq) {
                float v[4];
                int bi[4] = {idr[it].x, idr[it].y, idr[it].z, idr[it].w};
                unsigned wa[4] = {war[it].x, war[it].z, wbr[it].x, wbr[it].z};
                unsigned wb[4] = {war[it].y, war[it].w, wbr[it].y, wbr[it].w};
                #pragma unroll
                for (int p2 = 0; p2 < 4; ++p2) {
                    int bb = bi[p2];
                    float t00 = lm[bb], t01 = lm[bb + 1];
                    float t10 = lm[bb + HW], t11 = lm[bb + HW + 1];
                    float vv = asf(wa[p2] << 16) * t00 + asf(wa[p2] & 0xffff0000u) * t01
                             + asf(wb[p2] << 16) * t10 + asf(wb[p2] & 0xffff0000u) * t11;
                    if (sig) vv = __builtin_amdgcn_rcpf(1.f + __expf(-vv));
                    v[p2] = vv;
                }
                ushort4_t o = {f2bf(v[0]), f2bf(v[1]), f2bf(v[2]), f2bf(v[3])};
                o4[q] = o;
                sum += (v[0] + v[1]) + (v[2] + v[3]);
            }
        }
        #pragma unroll
        for (int m2 = 32; m2 > 0; m2 >>= 1) sum += __shfl_xor(sum, m2, 64);
        if ((tid & 63) == 0) spart[(size_t)(tid >> 6) * NM + mi] = sum;

        mi = nmi;
        cur ^= 1;
        p ^= 1;
    }
}

// ---------- kernel 3: MFMA split-K GEMM: Cpart[ks][n][t] = sum_k S[n,k]*Tm[t,k] ----------
#define LDF(Aarr, Barr, kof)                                                              \
    do {                                                                                  \
        _Pragma("unroll") for (int m_ = 0; m_ < 3; ++m_)                                  \
            Aarr[m_] = *(const short8*)(pa + (size_t)m_ * 16 * P + (kof));                \
        _Pragma("unroll") for (int j_ = 0; j_ < 5; ++j_)                                  \
            Barr[j_] = *(const short8*)(pb + (size_t)j_ * 16 * P + (kof));                \
    } while (0)

#define FMAS(Aarr, Barr)                                                                  \
    do {                                                                                  \
        _Pragma("unroll") for (int m_ = 0; m_ < 3; ++m_) {                                \
            _Pragma("unroll") for (int j_ = 0; j_ < 5; ++j_)                              \
                acc[m_][j_] = __builtin_amdgcn_mfma_f32_16x16x32_bf16(                    \
                    Aarr[m_], Barr[j_], acc[m_][j_], 0, 0, 0);                            \
        }                                                                                 \
    } while (0)

__global__ __launch_bounds__(256) void kgemm(const ushort_t* __restrict__ S,
                                             const ushort_t* __restrict__ Tm,
                                             float* __restrict__ Cpart,
                                             const int* __restrict__ lvl,
                                             int N, int T, int P, int nsteps) {
    if (*lvl >= 2) return;
    int tid = threadIdx.x;
    int wid = tid >> 6, lane = tid & 63;
    int wm = wid >> 1, wt = wid & 1;
    int r = lane & 15, g = lane >> 4;
    int n0 = blockIdx.x * 96 + wm * 48;
    int t0 = wt * 80;
    size_t k0 = (size_t)blockIdx.y * nsteps * 32 + g * 8;
    const ushort_t* pa = S + (size_t)(n0 + r) * P + k0;
    const ushort_t* pb = Tm + (size_t)(t0 + r) * P + k0;

    f32x4 acc[3][5];
    #pragma unroll
    for (int m2 = 0; m2 < 3; ++m2)
        #pragma unroll
        for (int j2 = 0; j2 < 5; ++j2) acc[m2][j2] = (f32x4){0.f, 0.f, 0.f, 0.f};

    short8 a0[3], b0[5], a1[3], b1[5];
    LDF(a0, b0, 0);
    int ks = 0;
    for (; ks + 2 < nsteps; ks += 2) {
        LDF(a1, b1, (ks + 1) * 32);
        FMAS(a0, b0);
        LDF(a0, b0, (ks + 2) * 32);
        FMAS(a1, b1);
    }
    LDF(a1, b1, (ks + 1) * 32);
    FMAS(a0, b0);
    FMAS(a1, b1);

    size_t cb = (size_t)blockIdx.y * N * T;
    #pragma unroll
    for (int m2 = 0; m2 < 3; ++m2)
        #pragma unroll
        for (int j2 = 0; j2 < 5; ++j2)
            #pragma unroll
            for (int q = 0; q < 4; ++q) {
                int row = n0 + m2 * 16 + g * 4 + q;
                int col = t0 + j2 * 16 + r;
                Cpart[cb + (size_t)row * T + col] = acc[m2][j2][q];
            }
}

// ---------- kernel 4: epilogue ----------
__global__ void kfinal(const float* __restrict__ logits, const float* __restrict__ opts,
                       const float* __restrict__ tpts, const float* __restrict__ Cpart,
                       const float* __restrict__ spart,
                       const int* __restrict__ lvl, float* __restrict__ out,
                       int N, int T, int nks) {
    int idx = blockIdx.x * 256 + threadIdx.x;
    if (idx >= N * T) return;
    int n = idx / T, t = idx - n * T;

    float lg = logits[n];
    float p = 1.f / (1.f + __expf(-lg));
    float pos = 0.25f * (1.f - p) * (1.f - p) * (-logf(p + 1e-8f));
    float neg = 0.75f * p * p * (-logf(1.f - p + 1e-8f));
    float ccls = pos - neg;

    float kp = 0.f;
    const float4* a4 = (const float4*)(opts + (size_t)n * 32);
    const float4* b4 = (const float4*)(tpts + (size_t)t * 32);
    #pragma unroll
    for (int j = 0; j < 8; ++j) {
        float4 a = a4[j], b = b4[j];
        kp += fabsf(a.x - b.x) + fabsf(a.y - b.y) + fabsf(a.z - b.z) + fabsf(a.w - b.w);
    }

    float dice = 0.f;
    if (*lvl < 2) {
        float dot = 0.f;
        for (int ks = 0; ks < nks; ++ks) dot += Cpart[(size_t)ks * N * T + idx];
        int NM = N + T;
        float sn = 0.f, st = 0.f;
        #pragma unroll
        for (int w2 = 0; w2 < SBLK / 64; ++w2) {
            sn += spart[(size_t)w2 * NM + n];
            st += spart[(size_t)w2 * NM + N + t];
        }
        dice = 1.f - (2.f * dot + 1.f) / (sn + st + 1.f);
    }
    out[idx] = 2.f * ccls + 5.f * kp + 5.f * dice;
}

extern "C" void kernel_launch(void* const* d_in, const int* in_sizes, int n_in,
                              void* d_out, int out_size, void* d_ws, size_t ws_size,
                              hipStream_t stream) {
    const float* logits = (const float*)d_in[0];
    const float* cpts   = (const float*)d_in[1];
    const float* pmask  = (const float*)d_in[2];
    const float* tpts   = (const float*)d_in[3];
    const float* tmasks = (const float*)d_in[4];
    const float* coords = (const float*)d_in[5];
    const int*   lvl    = (const int*)d_in[6];
    float* out = (float*)d_out;

    int N = in_sizes[0];        // 2400
    int T = in_sizes[3] / 32;   // 160
    int P = in_sizes[5] / 2;    // 12544
    int NM = N + T;

    char* w = (char*)d_ws;
    auto alloc = [&](size_t bytes) {
        char* r = w;
        w += (bytes + 255) & ~(size_t)255;
        return r;
    };
    int*      idxb  = (int*)alloc((size_t)P * 4);
    uint2*    wpkb  = (uint2*)alloc((size_t)P * 8);
    ushort_t* tsamp = (ushort_t*)alloc((size_t)T * P * 2);
    ushort_t* S     = (ushort_t*)alloc((size_t)N * P * 2);
    float*    spart = (float*)alloc((size_t)(SBLK / 64) * NM * 4);
    int*      ctr   = (int*)alloc(256);
    size_t base_bytes = (size_t)(w - (char*)d_ws);

    int nks = 28;
    if (base_bytes + (size_t)nks * N * T * 4 > ws_size) nks = 14;
    if (base_bytes + (size_t)nks * N * T * 4 > ws_size) nks = 7;
    int nsteps = (P / 32) / nks;
    float* Cpart = (float*)alloc((size_t)nks * N * T * 4);

    kprep<<<(P + 255) / 256, 256, 0, stream>>>(coords, idxb, wpkb, ctr, P);
    ksamp_all<<<NBLK, SBLK, 0, stream>>>(pmask, tmasks, idxb, wpkb, S, tsamp,
                                         spart, ctr, lvl, N, T, P);
    kgemm<<<dim3(N / 96, nks), 256, 0, stream>>>(S, tsamp, Cpart, lvl, N, T, P, nsteps);
    kfinal<<<(N * T + 255) / 256, 256, 0, stream>>>(logits, cpts, tpts, Cpart, spart,
                                                    lvl, out, N, T, nks);
}